// Round 1
// baseline (157.660 us; speedup 1.0000x reference)
//
#include <hip/hip_runtime.h>

#define HH 128
#define WW 128
#define HW 16384
#define KK 16
#define NPTS 16384
#define FEAT 64
#define RADIUS2 4.0f
#define EPSV 1e-10f

// ---------------- kernel 1: project points, count per-cell ----------------
__global__ void project_kernel(const float* __restrict__ pts,
                               const float* __restrict__ intr,
                               float* __restrict__ pu, float* __restrict__ pv,
                               float* __restrict__ pd, int* __restrict__ cell_of,
                               int* __restrict__ cell_count) {
    int n = blockIdx.x * blockDim.x + threadIdx.x;
    if (n >= NPTS) return;
    float fx = intr[0], cx = intr[2], fy = intr[4], cy = intr[5];
    float x = pts[3 * n], y = pts[3 * n + 1], z = pts[3 * n + 2];
    bool valid = z > 1e-6f;
    float sz = valid ? z : 1.0f;
    float u = x * fx / sz + cx;
    float v = y * fy / sz + cy;
    if (!valid) { u = 1e9f; v = 1e9f; }
    pu[n] = u; pv[n] = v; pd[n] = z;
    int cell = -1;
    if (valid) {
        int cu = (int)floorf(u); cu = min(max(cu, 0), WW - 1);
        int cv = (int)floorf(v); cv = min(max(cv, 0), HH - 1);
        cell = cv * WW + cu;
        atomicAdd(&cell_count[cell], 1);
    }
    cell_of[n] = cell;
}

// ---------------- kernel 2: exclusive prefix scan over 16384 cells ----------------
__global__ void scan_kernel(const int* __restrict__ count, int* __restrict__ start,
                            int* __restrict__ cursor) {
    __shared__ int partials[256];
    __shared__ int scanned[257];
    int tid = threadIdx.x;
    int base = tid * 64;
    int s = 0;
    for (int i = 0; i < 64; ++i) s += count[base + i];
    partials[tid] = s;
    __syncthreads();
    if (tid == 0) {
        int acc = 0;
        for (int t = 0; t < 256; ++t) { scanned[t] = acc; acc += partials[t]; }
        scanned[256] = acc;
    }
    __syncthreads();
    int acc = scanned[tid];
    for (int i = 0; i < 64; ++i) {
        int c = count[base + i];
        start[base + i] = acc;
        cursor[base + i] = acc;
        acc += c;
    }
    if (tid == 255) start[HW] = scanned[256];
}

// ---------------- kernel 3: scatter points into cell-sorted arrays ----------------
__global__ void scatter_kernel(const float* __restrict__ pu, const float* __restrict__ pv,
                               const float* __restrict__ pd, const int* __restrict__ cell_of,
                               int* __restrict__ cursor,
                               float* __restrict__ su, float* __restrict__ sv,
                               float* __restrict__ sd, int* __restrict__ sid) {
    int n = blockIdx.x * blockDim.x + threadIdx.x;
    if (n >= NPTS) return;
    int cell = cell_of[n];
    if (cell < 0) return;
    int pos = atomicAdd(&cursor[cell], 1);
    su[pos] = pu[n]; sv[pos] = pv[n]; sd[pos] = pd[n]; sid[pos] = n;
}

// ---------------- kernel 4: per-pixel KNN + depth/color/mask ----------------
__global__ void render_kernel(const float* __restrict__ su, const float* __restrict__ sv,
                              const float* __restrict__ sd, const int* __restrict__ sid,
                              const int* __restrict__ start,
                              const float* __restrict__ colors,
                              float* __restrict__ out_depth, float* __restrict__ out_colors,
                              float* __restrict__ out_mask,
                              int* __restrict__ knn_idx, float* __restrict__ knn_w) {
    int p = blockIdx.x * blockDim.x + threadIdx.x;
    if (p >= HW) return;
    int i = p >> 7, j = p & (WW - 1);
    float px = j + 0.5f, py = i + 0.5f;

    float bd[KK];  // sorted ascending d2
    int   bt[KK];  // slot in sorted point arrays
#pragma unroll
    for (int k = 0; k < KK; ++k) { bd[k] = 1e30f; bt[k] = -1; }

    int ci0 = max(i - 2, 0), ci1 = min(i + 2, HH - 1);
    int cj0 = max(j - 2, 0), cj1 = min(j + 2, WW - 1);
    for (int ci = ci0; ci <= ci1; ++ci) {
        int rowbase = ci * WW;
        // cells cj0..cj1 are contiguous in the sorted arrays
        int s0 = start[rowbase + cj0];
        int s1 = start[rowbase + cj1 + 1];
        for (int t = s0; t < s1; ++t) {
            float du = su[t] - px, dv = sv[t] - py;
            float d2 = du * du + dv * dv;
            if (d2 < RADIUS2) {
                float dd = d2; int tt = t;
#pragma unroll
                for (int k = 0; k < KK; ++k) {
                    if (dd < bd[k]) {
                        float f = bd[k]; bd[k] = dd; dd = f;
                        int   q = bt[k]; bt[k] = tt; tt = q;
                    }
                }
            }
        }
    }

    float w[KK];
    float wsum = 0.f;
#pragma unroll
    for (int k = 0; k < KK; ++k) {
        float wk = 0.f;
        if (bt[k] >= 0) {
            float dist = sqrtf(bd[k]);
            wk = expf(-dist * dist);  // SIGMA = 1
        }
        w[k] = wk; wsum += wk;
    }
    float inv = 1.0f / (wsum + EPSV);

    float dsum = 0.f, c0 = 0.f, c1 = 0.f, c2 = 0.f;
    bool any = false;
#pragma unroll
    for (int k = 0; k < KK; ++k) {
        int t = bt[k];
        float wk = w[k] * inv;
        knn_w[p * KK + k] = wk;
        int n = -1;
        if (t >= 0) {
            any = true;
            n = sid[t];
            dsum += sd[t] * wk;
            c0 += colors[3 * n]     * wk;
            c1 += colors[3 * n + 1] * wk;
            c2 += colors[3 * n + 2] * wk;
        }
        knn_idx[p * KK + k] = n;
    }
    out_depth[p] = dsum;
    out_colors[3 * p]     = c0;
    out_colors[3 * p + 1] = c1;
    out_colors[3 * p + 2] = c2;
    out_mask[p] = any ? 1.0f : 0.0f;
}

// ---------------- kernel 5: feats accumulation, wave-per-pixel ----------------
__global__ void feats_kernel(const float* __restrict__ feats,
                             const int* __restrict__ knn_idx,
                             const float* __restrict__ knn_w,
                             float* __restrict__ out_feats) {
    int p = blockIdx.x * blockDim.y + threadIdx.y;
    int f = threadIdx.x;  // 0..63
    float acc = 0.f;
#pragma unroll
    for (int k = 0; k < KK; ++k) {
        int n = knn_idx[p * KK + k];
        float wk = knn_w[p * KK + k];
        if (n >= 0) acc += wk * feats[n * FEAT + f];
    }
    out_feats[p * FEAT + f] = acc;
}

extern "C" void kernel_launch(void* const* d_in, const int* in_sizes, int n_in,
                              void* d_out, int out_size, void* d_ws, size_t ws_size,
                              hipStream_t stream) {
    const float* pts    = (const float*)d_in[0];
    const float* colors = (const float*)d_in[1];
    const float* feats  = (const float*)d_in[2];
    const float* intr   = (const float*)d_in[3];

    float* out = (float*)d_out;
    float* out_depth  = out;                  // HW
    float* out_colors = out + HW;             // HW*3
    float* out_feats  = out + HW * 4;         // HW*64
    float* out_mask   = out + HW * 68;        // HW

    // workspace layout: 16448-element slots (64B-aligned)
    const size_t SLOT = 16448;
    char* ws = (char*)d_ws;
    float* pu       = (float*)(ws + 0 * SLOT * 4);
    float* pv       = (float*)(ws + 1 * SLOT * 4);
    float* pd       = (float*)(ws + 2 * SLOT * 4);
    int* cell_of    = (int*)  (ws + 3 * SLOT * 4);
    int* cell_count = (int*)  (ws + 4 * SLOT * 4);
    int* start      = (int*)  (ws + 5 * SLOT * 4);  // HW+1
    int* cursor     = (int*)  (ws + 6 * SLOT * 4);
    float* su       = (float*)(ws + 7 * SLOT * 4);
    float* sv       = (float*)(ws + 8 * SLOT * 4);
    float* sd       = (float*)(ws + 9 * SLOT * 4);
    int* sid        = (int*)  (ws + 10 * SLOT * 4);
    int* knn_idx    = (int*)  (ws + 11 * SLOT * 4);             // HW*16
    float* knn_w    = (float*)(ws + 11 * SLOT * 4 + HW * KK * 4); // HW*16

    hipMemsetAsync(cell_count, 0, HW * sizeof(int), stream);

    project_kernel<<<NPTS / 256, 256, 0, stream>>>(pts, intr, pu, pv, pd, cell_of, cell_count);
    scan_kernel<<<1, 256, 0, stream>>>(cell_count, start, cursor);
    scatter_kernel<<<NPTS / 256, 256, 0, stream>>>(pu, pv, pd, cell_of, cursor, su, sv, sd, sid);
    render_kernel<<<HW / 256, 256, 0, stream>>>(su, sv, sd, sid, start, colors,
                                                out_depth, out_colors, out_mask, knn_idx, knn_w);
    dim3 fb(FEAT, 4);
    feats_kernel<<<HW / 4, fb, 0, stream>>>(feats, knn_idx, knn_w, out_feats);
}

// Round 2
// 105.094 us; speedup vs baseline: 1.5002x; 1.5002x over previous
//
#include <hip/hip_runtime.h>

#define HH 128
#define WW 128
#define HW 16384
#define KK 16
#define NPTS 16384
#define FEAT 64
#define RADIUS2 4.0f
#define EPSV 1e-10f
#define CH 16

// ---------------- kernel 1: project points, count per-cell ----------------
__global__ void project_kernel(const float* __restrict__ pts,
                               const float* __restrict__ intr,
                               float2* __restrict__ puv,
                               float* __restrict__ pd, int* __restrict__ cell_of,
                               int* __restrict__ cell_count) {
    int n = blockIdx.x * blockDim.x + threadIdx.x;
    if (n >= NPTS) return;
    float fx = intr[0], cx = intr[2], fy = intr[4], cy = intr[5];
    float x = pts[3 * n], y = pts[3 * n + 1], z = pts[3 * n + 2];
    bool valid = z > 1e-6f;
    float sz = valid ? z : 1.0f;
    float u = x * fx / sz + cx;
    float v = y * fy / sz + cy;
    if (!valid) { u = 1e9f; v = 1e9f; }
    puv[n] = make_float2(u, v);
    pd[n] = z;
    int cell = -1;
    if (valid) {
        int cu = (int)floorf(u); cu = min(max(cu, 0), WW - 1);
        int cv = (int)floorf(v); cv = min(max(cv, 0), HH - 1);
        cell = cv * WW + cu;
        atomicAdd(&cell_count[cell], 1);
    }
    cell_of[n] = cell;
}

// ---------------- kernel 2: exclusive prefix scan over 16384 cells ----------------
__global__ void scan_kernel(const int* __restrict__ count, int* __restrict__ start,
                            int* __restrict__ cursor) {
    __shared__ int partials[256];
    __shared__ int scanned[257];
    int tid = threadIdx.x;
    int base = tid * 64;
    int s = 0;
#pragma unroll
    for (int i = 0; i < 64; ++i) s += count[base + i];
    partials[tid] = s;
    __syncthreads();
    if (tid == 0) {
        int acc = 0;
        for (int t = 0; t < 256; ++t) { scanned[t] = acc; acc += partials[t]; }
        scanned[256] = acc;
    }
    __syncthreads();
    int acc = scanned[tid];
#pragma unroll
    for (int i = 0; i < 64; ++i) {
        int c = count[base + i];
        start[base + i] = acc;
        cursor[base + i] = acc;
        acc += c;
    }
    if (tid == 255) start[HW] = scanned[256];
}

// ---------------- kernel 3: scatter into cell-sorted arrays ----------------
__global__ void scatter_kernel(const float2* __restrict__ puv,
                               const float* __restrict__ pd, const int* __restrict__ cell_of,
                               int* __restrict__ cursor,
                               float2* __restrict__ suv,
                               float* __restrict__ sd, int* __restrict__ sid) {
    int n = blockIdx.x * blockDim.x + threadIdx.x;
    if (n >= NPTS) return;
    int cell = cell_of[n];
    if (cell < 0) return;
    int pos = atomicAdd(&cursor[cell], 1);
    suv[pos] = puv[n];
    sd[pos] = pd[n];
    sid[pos] = n;
}

// ---------------- kernel 4: per-pixel KNN + depth/color/mask ----------------
__global__ __launch_bounds__(64) void render_kernel(
        const float2* __restrict__ suv,
        const float* __restrict__ sd, const int* __restrict__ sid,
        const int* __restrict__ start,
        const float* __restrict__ colors,
        float* __restrict__ out_depth, float* __restrict__ out_colors,
        float* __restrict__ out_mask,
        int* __restrict__ knn_idx, float* __restrict__ knn_w) {
    int p = blockIdx.x * 64 + threadIdx.x;
    int i = p >> 7, j = p & (WW - 1);
    float px = j + 0.5f, py = i + 0.5f;

    // ---- row-segment setup: 10 independent start[] loads ----
    int cj0 = max(j - 2, 0);
    int cj1e = min(j + 2, WW - 1) + 1;
    int o[5];   // cumulative candidate offsets (o[0]=0)
    int dadj[5]; // t = g + dadj[seg]
    int tot = 0;
#pragma unroll
    for (int r = 0; r < 5; ++r) {
        int ci = i - 2 + r;
        int s0 = 0, s1 = 0;
        if (ci >= 0 && ci < HH) {
            s0 = start[ci * WW + cj0];
            s1 = start[ci * WW + cj1e];
        }
        o[r] = tot;
        dadj[r] = s0 - tot;
        tot += s1 - s0;
    }

    float bd[KK];
    int   bt[KK];
#pragma unroll
    for (int k = 0; k < KK; ++k) { bd[k] = 1e30f; bt[k] = -1; }

    // ---- chunked, pipelined candidate processing ----
    int b = 0;
    while (__ballot(b < tot) != 0ull) {
        float2 uv[CH];
        int    tc[CH];
#pragma unroll
        for (int c = 0; c < CH; ++c) {
            int g = b + c;
            int ds = dadj[0];
            ds = (g >= o[1]) ? dadj[1] : ds;
            ds = (g >= o[2]) ? dadj[2] : ds;
            ds = (g >= o[3]) ? dadj[3] : ds;
            ds = (g >= o[4]) ? dadj[4] : ds;
            int t = g + ds;
            bool val = g < tot;
            tc[c] = val ? t : -1;
            uv[c] = suv[val ? t : 0];
        }
#pragma unroll
        for (int c = 0; c < CH; ++c) {
            float du = uv[c].x - px, dv = uv[c].y - py;
            float d2 = du * du + dv * dv;
            float dd = (tc[c] >= 0 && d2 < RADIUS2) ? d2 : 1e30f;
            int tt = tc[c];
#pragma unroll
            for (int k = 0; k < KK; ++k) {
                bool cc2 = dd < bd[k];
                float nb = cc2 ? dd : bd[k];
                dd = cc2 ? bd[k] : dd;
                int nt = cc2 ? tt : bt[k];
                tt = cc2 ? bt[k] : tt;
                bd[k] = nb; bt[k] = nt;
            }
        }
        b += CH;
    }

    // ---- weights ----
    float w[KK];
    float wsum = 0.f;
#pragma unroll
    for (int k = 0; k < KK; ++k) {
        bool v = bt[k] >= 0;
        float wk = v ? __expf(-bd[k]) : 0.f;  // SIGMA=1, exp(-d2)
        w[k] = wk; wsum += wk;
    }
    float inv = 1.0f / (wsum + EPSV);

    // ---- batched winner gathers: sd/sid first, then colors ----
    float dep[KK]; int nn[KK];
#pragma unroll
    for (int k = 0; k < KK; ++k) {
        int t = bt[k];
        int ta = t >= 0 ? t : 0;
        dep[k] = sd[ta];
        nn[k] = sid[ta];
    }
    float cr[KK], cg[KK], cb[KK];
#pragma unroll
    for (int k = 0; k < KK; ++k) {
        int n3 = 3 * nn[k];
        cr[k] = colors[n3];
        cg[k] = colors[n3 + 1];
        cb[k] = colors[n3 + 2];
    }

    float dsum = 0.f, c0 = 0.f, c1 = 0.f, c2 = 0.f;
    bool any = false;
    int   idx_out[KK];
    float w_out[KK];
#pragma unroll
    for (int k = 0; k < KK; ++k) {
        bool v = bt[k] >= 0;
        float wk = w[k] * inv;     // 0 for invalid slots
        any = any || v;
        idx_out[k] = v ? nn[k] : -1;
        w_out[k] = wk;
        dsum += dep[k] * wk;
        c0 += cr[k] * wk;
        c1 += cg[k] * wk;
        c2 += cb[k] * wk;
    }

    // vectorized knn handoff stores
    int4*   ki4 = (int4*)(knn_idx + p * KK);
    float4* kw4 = (float4*)(knn_w + p * KK);
#pragma unroll
    for (int q = 0; q < 4; ++q) {
        ki4[q] = make_int4(idx_out[4 * q], idx_out[4 * q + 1], idx_out[4 * q + 2], idx_out[4 * q + 3]);
        kw4[q] = make_float4(w_out[4 * q], w_out[4 * q + 1], w_out[4 * q + 2], w_out[4 * q + 3]);
    }

    out_depth[p] = dsum;
    out_colors[3 * p]     = c0;
    out_colors[3 * p + 1] = c1;
    out_colors[3 * p + 2] = c2;
    out_mask[p] = any ? 1.0f : 0.0f;
}

// ---------------- kernel 5: feats accumulation, wave-per-pixel ----------------
__global__ void feats_kernel(const float* __restrict__ feats,
                             const int* __restrict__ knn_idx,
                             const float* __restrict__ knn_w,
                             float* __restrict__ out_feats) {
    int p = blockIdx.x * blockDim.y + threadIdx.y;
    int f = threadIdx.x;  // 0..63
    int nn[KK]; float wk[KK];
#pragma unroll
    for (int k = 0; k < KK; ++k) {
        nn[k] = knn_idx[p * KK + k];
        wk[k] = knn_w[p * KK + k];
    }
    float acc = 0.f;
    float fv[KK];
#pragma unroll
    for (int k = 0; k < KK; ++k) {
        int n = nn[k] >= 0 ? nn[k] : 0;
        fv[k] = feats[n * FEAT + f];
    }
#pragma unroll
    for (int k = 0; k < KK; ++k) {
        float m = nn[k] >= 0 ? wk[k] : 0.f;
        acc += m * fv[k];
    }
    out_feats[p * FEAT + f] = acc;
}

extern "C" void kernel_launch(void* const* d_in, const int* in_sizes, int n_in,
                              void* d_out, int out_size, void* d_ws, size_t ws_size,
                              hipStream_t stream) {
    const float* pts    = (const float*)d_in[0];
    const float* colors = (const float*)d_in[1];
    const float* feats  = (const float*)d_in[2];
    const float* intr   = (const float*)d_in[3];

    float* out = (float*)d_out;
    float* out_depth  = out;                  // HW
    float* out_colors = out + HW;             // HW*3
    float* out_feats  = out + HW * 4;         // HW*64
    float* out_mask   = out + HW * 68;        // HW

    // workspace layout: 16448-element slots (64B-aligned)
    const size_t SLOT = 16448;
    char* ws = (char*)d_ws;
    float2* puv     = (float2*)(ws + 0 * SLOT * 4);            // 2 slots
    float* pd       = (float*)(ws + 2 * SLOT * 4);
    int* cell_of    = (int*)  (ws + 3 * SLOT * 4);
    int* cell_count = (int*)  (ws + 4 * SLOT * 4);
    int* start      = (int*)  (ws + 5 * SLOT * 4);  // HW+1
    int* cursor     = (int*)  (ws + 6 * SLOT * 4);
    float2* suv     = (float2*)(ws + 7 * SLOT * 4);            // 2 slots
    float* sd       = (float*)(ws + 9 * SLOT * 4);
    int* sid        = (int*)  (ws + 10 * SLOT * 4);
    int* knn_idx    = (int*)  (ws + 11 * SLOT * 4);             // HW*16
    float* knn_w    = (float*)(ws + 11 * SLOT * 4 + HW * KK * 4); // HW*16

    hipMemsetAsync(cell_count, 0, HW * sizeof(int), stream);

    project_kernel<<<NPTS / 256, 256, 0, stream>>>(pts, intr, puv, pd, cell_of, cell_count);
    scan_kernel<<<1, 256, 0, stream>>>(cell_count, start, cursor);
    scatter_kernel<<<NPTS / 256, 256, 0, stream>>>(puv, pd, cell_of, cursor, suv, sd, sid);
    render_kernel<<<HW / 64, 64, 0, stream>>>(suv, sd, sid, start, colors,
                                              out_depth, out_colors, out_mask, knn_idx, knn_w);
    dim3 fb(FEAT, 4);
    feats_kernel<<<HW / 4, fb, 0, stream>>>(feats, knn_idx, knn_w, out_feats);
}

// Round 3
// 99.268 us; speedup vs baseline: 1.5882x; 1.0587x over previous
//
#include <hip/hip_runtime.h>

#define HH 128
#define WW 128
#define HW 16384
#define KK 16
#define NPTS 16384
#define FEAT 64
#define RADIUS2 4.0f
#define EPSV 1e-10f

// ---------------- kernel 1: project points, count per-cell ----------------
__global__ void project_kernel(const float* __restrict__ pts,
                               const float* __restrict__ intr,
                               float4* __restrict__ puvdi,
                               int* __restrict__ cell_of,
                               int* __restrict__ cell_count) {
    int n = blockIdx.x * blockDim.x + threadIdx.x;
    if (n >= NPTS) return;
    float fx = intr[0], cx = intr[2], fy = intr[4], cy = intr[5];
    float x = pts[3 * n], y = pts[3 * n + 1], z = pts[3 * n + 2];
    bool valid = z > 1e-6f;
    float sz = valid ? z : 1.0f;
    float u = x * fx / sz + cx;
    float v = y * fy / sz + cy;
    if (!valid) { u = 1e9f; v = 1e9f; }
    puvdi[n] = make_float4(u, v, z, __int_as_float(n));
    int cell = -1;
    if (valid) {
        int cu = (int)floorf(u); cu = min(max(cu, 0), WW - 1);
        int cv = (int)floorf(v); cv = min(max(cv, 0), HH - 1);
        cell = cv * WW + cu;
        atomicAdd(&cell_count[cell], 1);
    }
    cell_of[n] = cell;
}

// ---------------- kernel 2: prefix scan over 16384 cells (wave-shuffle) ----------------
__global__ __launch_bounds__(256) void scan_kernel(const int4* __restrict__ count4,
                                                   int* __restrict__ start,
                                                   int* __restrict__ cursor) {
    __shared__ int wsum_s[4];
    int tid = threadIdx.x;
    int4 c[16];
#pragma unroll
    for (int q = 0; q < 16; ++q) c[q] = count4[tid * 16 + q];
    int s = 0;
#pragma unroll
    for (int q = 0; q < 16; ++q) s += c[q].x + c[q].y + c[q].z + c[q].w;
    int lane = tid & 63, wv = tid >> 6;
    int incl = s;
#pragma unroll
    for (int d = 1; d < 64; d <<= 1) {
        int t = __shfl_up(incl, d, 64);
        if (lane >= d) incl += t;
    }
    if (lane == 63) wsum_s[wv] = incl;
    __syncthreads();
    int wbase = 0;
#pragma unroll
    for (int q = 0; q < 4; ++q) wbase += (q < wv) ? wsum_s[q] : 0;
    int acc = wbase + incl - s;  // exclusive base for this thread's 64 cells
    int base = tid * 64;
#pragma unroll
    for (int q = 0; q < 16; ++q) {
        int4 st;
        st.x = acc; acc += c[q].x;
        st.y = acc; acc += c[q].y;
        st.z = acc; acc += c[q].z;
        st.w = acc; acc += c[q].w;
        ((int4*)(start + base))[q] = st;
        ((int4*)(cursor + base))[q] = st;
    }
    if (tid == 255) start[HW] = acc;
}

// ---------------- kernel 3: scatter into cell-sorted float4 array ----------------
__global__ void scatter_kernel(const float4* __restrict__ puvdi,
                               const int* __restrict__ cell_of,
                               int* __restrict__ cursor,
                               float4* __restrict__ suvdi) {
    int n = blockIdx.x * blockDim.x + threadIdx.x;
    if (n >= NPTS) return;
    int cell = cell_of[n];
    if (cell < 0) return;
    int pos = atomicAdd(&cursor[cell], 1);
    suvdi[pos] = puvdi[n];
}

// ---------------- kernel 4: tiled per-pixel KNN, 2 lanes/pixel ----------------
// block = 64 threads = 2 lanes x 32 pixels (8 wide x 4 tall tile); grid = 512
__global__ __launch_bounds__(64) void render_kernel(
        const float4* __restrict__ suvdi,
        const int* __restrict__ start,
        const float* __restrict__ colors,
        float* __restrict__ out_depth, float* __restrict__ out_colors,
        float* __restrict__ out_mask,
        int* __restrict__ knn_idx, float* __restrict__ knn_w) {
    __shared__ float4 pts_s[1024];
    __shared__ int S[8][13];
    __shared__ int row_off[9];

    int tid = threadIdx.x;
    int tile = blockIdx.x;
    int j0 = (tile & 15) * 8;
    int i0 = (tile >> 4) * 4;

    // ---- stage start[] sub-table: rows i0-2..i0+5, cols j0-2..j0+10 ----
    for (int idx = tid; idx < 104; idx += 64) {
        int r = idx / 13, c = idx - r * 13;
        int ci = i0 - 2 + r;
        int col = min(max(j0 - 2 + c, 0), 128);
        int v = 0;
        if (ci >= 0 && ci < HH) v = start[ci * WW + col];
        S[r][c] = v;
    }
    __syncthreads();
    if (tid == 0) {
        int acc = 0;
#pragma unroll
        for (int r = 0; r < 8; ++r) { row_off[r] = acc; acc += S[r][12] - S[r][0]; }
        row_off[8] = acc;
    }
    __syncthreads();
    int T = min(row_off[8], 1024);

    // ---- stage candidate points into LDS ----
    for (int idx = tid; idx < T; idx += 64) {
        int r = 0;
#pragma unroll
        for (int q = 1; q < 8; ++q) r = (idx >= row_off[q]) ? q : r;
        int g = S[r][0] + (idx - row_off[r]);
        pts_s[idx] = suvdi[g];
    }
    __syncthreads();

    // ---- per-pixel scan, 2 lanes/pixel ----
    int lp = tid >> 1, lane = tid & 1;
    int li = lp >> 3, lj = lp & 7;
    int i = i0 + li, j = j0 + lj;
    int p = i * WW + j;
    float px = j + 0.5f, py = i + 0.5f;
    int ca = max(j - 2, 0) - (j0 - 2);
    int cb = min(j + 2, WW - 1) + 1 - (j0 - 2);

    float bd[KK];
    int   bt[KK];
#pragma unroll
    for (int k = 0; k < KK; ++k) { bd[k] = 1e30f; bt[k] = -1; }

#pragma unroll
    for (int dr = 0; dr < 5; ++dr) {
        int r = li + dr;
        int g0 = S[r][ca], g1 = S[r][cb];
        int base = row_off[r] - S[r][0];
        for (int g = g0 + lane; g < g1; g += 2) {
            float4 pt = pts_s[base + g];
            float du = pt.x - px, dv = pt.y - py;
            float d2 = du * du + dv * dv;
            bool ok = d2 < RADIUS2;
            float dd = ok ? d2 : 1e30f;
            int tt = ok ? (base + g) : -1;
#pragma unroll
            for (int k = 0; k < KK; ++k) {
                bool cc = dd < bd[k];
                float nb = cc ? dd : bd[k];
                dd = cc ? bd[k] : dd;
                int nt = cc ? tt : bt[k];
                tt = cc ? bt[k] : tt;
                bd[k] = nb; bt[k] = nt;
            }
        }
    }

    // ---- cross-lane bitonic min-merge: lane keeps 8 disjoint winners ----
    float mb[8]; int mt[8];
#pragma unroll
    for (int k = 0; k < 8; ++k) {
        float obd = __shfl_xor(bd[15 - k], 1);
        int   obt = __shfl_xor(bt[15 - k], 1);
        bool take = obd < bd[k];
        mb[k] = take ? obd : bd[k];
        mt[k] = take ? obt : bt[k];
    }

    // ---- per-lane epilogue over 8 winners ----
    float wv[8], dv8[8];
    int idv[8];
    float wsum_l = 0.f;
    int any_l = 0;
#pragma unroll
    for (int k = 0; k < 8; ++k) {
        bool valid = mt[k] >= 0;
        float4 pt = pts_s[valid ? mt[k] : 0];
        float wk = valid ? __expf(-mb[k]) : 0.f;
        wv[k] = wk; wsum_l += wk;
        dv8[k] = valid ? pt.z : 0.f;
        idv[k] = valid ? __float_as_int(pt.w) : -1;
        any_l |= valid ? 1 : 0;
    }
    float wsum = wsum_l + __shfl_xor(wsum_l, 1);
    float inv = 1.0f / (wsum + EPSV);

    float cr[8], cg[8], cbl[8];
#pragma unroll
    for (int k = 0; k < 8; ++k) {
        int n3 = idv[k] >= 0 ? 3 * idv[k] : 0;
        cr[k] = colors[n3];
        cg[k] = colors[n3 + 1];
        cbl[k] = colors[n3 + 2];
    }

    float dsum = 0.f, c0 = 0.f, c1 = 0.f, c2 = 0.f;
    int   io[8]; float wo[8];
#pragma unroll
    for (int k = 0; k < 8; ++k) {
        float wk = wv[k] * inv;
        io[k] = idv[k];
        wo[k] = wk;
        dsum += dv8[k] * wk;
        c0 += cr[k] * wk;
        c1 += cg[k] * wk;
        c2 += cbl[k] * wk;
    }

    // handoff: lane 0 -> slots 0..7, lane 1 -> slots 8..15 (order-invariant)
    int4*   ki4 = (int4*)(knn_idx + p * KK + lane * 8);
    float4* kw4 = (float4*)(knn_w + p * KK + lane * 8);
    ki4[0] = make_int4(io[0], io[1], io[2], io[3]);
    ki4[1] = make_int4(io[4], io[5], io[6], io[7]);
    kw4[0] = make_float4(wo[0], wo[1], wo[2], wo[3]);
    kw4[1] = make_float4(wo[4], wo[5], wo[6], wo[7]);

    dsum += __shfl_xor(dsum, 1);
    c0 += __shfl_xor(c0, 1);
    c1 += __shfl_xor(c1, 1);
    c2 += __shfl_xor(c2, 1);
    any_l |= __shfl_xor(any_l, 1);

    if (lane == 0) {
        out_depth[p] = dsum;
        out_colors[3 * p]     = c0;
        out_colors[3 * p + 1] = c1;
        out_colors[3 * p + 2] = c2;
        out_mask[p] = any_l ? 1.0f : 0.0f;
    }
}

// ---------------- kernel 5: feats accumulation, wave-per-pixel ----------------
__global__ void feats_kernel(const float* __restrict__ feats,
                             const int* __restrict__ knn_idx,
                             const float* __restrict__ knn_w,
                             float* __restrict__ out_feats) {
    int p = blockIdx.x * blockDim.y + threadIdx.y;
    int f = threadIdx.x;  // 0..63
    int nn[KK]; float wk[KK];
#pragma unroll
    for (int k = 0; k < KK; ++k) {
        nn[k] = knn_idx[p * KK + k];
        wk[k] = knn_w[p * KK + k];
    }
    float fv[KK];
#pragma unroll
    for (int k = 0; k < KK; ++k) {
        int n = nn[k] >= 0 ? nn[k] : 0;
        fv[k] = feats[n * FEAT + f];
    }
    float acc = 0.f;
#pragma unroll
    for (int k = 0; k < KK; ++k) {
        float m = nn[k] >= 0 ? wk[k] : 0.f;
        acc += m * fv[k];
    }
    out_feats[p * FEAT + f] = acc;
}

extern "C" void kernel_launch(void* const* d_in, const int* in_sizes, int n_in,
                              void* d_out, int out_size, void* d_ws, size_t ws_size,
                              hipStream_t stream) {
    const float* pts    = (const float*)d_in[0];
    const float* colors = (const float*)d_in[1];
    const float* feats  = (const float*)d_in[2];
    const float* intr   = (const float*)d_in[3];

    float* out = (float*)d_out;
    float* out_depth  = out;                  // HW
    float* out_colors = out + HW;             // HW*3
    float* out_feats  = out + HW * 4;         // HW*64
    float* out_mask   = out + HW * 68;        // HW

    // workspace layout: 16448-element (65792 B, 16B-aligned) slots
    const size_t SLOT = 16448;
    char* ws = (char*)d_ws;
    float4* puvdi   = (float4*)(ws + 0 * SLOT * 4);   // slots 0-3
    int* cell_of    = (int*)   (ws + 4 * SLOT * 4);
    int* cell_count = (int*)   (ws + 5 * SLOT * 4);
    int* start      = (int*)   (ws + 6 * SLOT * 4);   // HW+1
    int* cursor     = (int*)   (ws + 7 * SLOT * 4);
    float4* suvdi   = (float4*)(ws + 8 * SLOT * 4);   // slots 8-11
    int* knn_idx    = (int*)   (ws + 12 * SLOT * 4);              // HW*16
    float* knn_w    = (float*) (ws + 12 * SLOT * 4 + HW * KK * 4); // HW*16

    hipMemsetAsync(cell_count, 0, HW * sizeof(int), stream);

    project_kernel<<<NPTS / 256, 256, 0, stream>>>(pts, intr, puvdi, cell_of, cell_count);
    scan_kernel<<<1, 256, 0, stream>>>((const int4*)cell_count, start, cursor);
    scatter_kernel<<<NPTS / 256, 256, 0, stream>>>(puvdi, cell_of, cursor, suvdi);
    render_kernel<<<512, 64, 0, stream>>>(suvdi, start, colors,
                                          out_depth, out_colors, out_mask, knn_idx, knn_w);
    dim3 fb(FEAT, 4);
    feats_kernel<<<HW / 4, fb, 0, stream>>>(feats, knn_idx, knn_w, out_feats);
}